// Round 19
// baseline (109.897 us; speedup 1.0000x reference)
//
#include <hip/hip_runtime.h>
#include <hip/hip_fp16.h>
#include <math.h>

#define S 256
#define A 180
#define B 4
#define RSW 265           // row stride in dwords (odd -> bank spread); 1 dword = 1 pixel-pair
#define NRW 69            // staged rows: 64 owned + 2 margin each side + 1 for y1
#define LDSW (NRW * RSW)  // 18,285 dwords = 73,140 B -> 2 blocks/CU

// Kernel 1: circle mask + pack batch-pairs: ws[c*65536 + p] = f16(b=2c) | f16(b=2c+1)<<16.
// Also zeroes the output sinogram (grid covers 184,320 threads).
__global__ void radon_mask_pack(const float* __restrict__ in, uint* __restrict__ ws,
                                float* __restrict__ osino) {
    int idx = blockIdx.x * 256 + threadIdx.x;    // 0 .. 184319
    if (idx < 2 * S * S) {
        int c = idx >> 16;          // batch pair 0/1
        int p = idx & 65535;
        int y = p >> 8;
        int x = p & 255;
        int dx = x - 128, dy = y - 128;
        bool inside = (dx * dx + dy * dy <= 16384);
        float v0 = in[(2 * c) * (S * S) + p];
        float v1 = in[(2 * c + 1) * (S * S) + p];
        v0 = inside ? v0 : 0.0f;
        v1 = inside ? v1 : 0.0f;
        uint lo = (uint)__half_as_ushort(__float2half(v0));
        uint hi = (uint)__half_as_ushort(__float2half(v1));
        ws[c * (S * S) + p] = lo | (hi << 16);
    }
    if (idx < A * B * S) osino[idx] = 0.0f;
}

// Kernel 2: grid (A, 2 batch-pairs, 4 y-strips of 64 rows), 512 threads =
// (j=tid>>1, q=tid&1) -> 25.5 pair-taps/thread (R18's 12.7 was latency-tail
// fragmentation). Block (a,c,h) owns taps with floor(py) in [64h, 64h+64)
// (py monotone in i; sn<0 at a=179 flips interval direction). Pixel-pair
// layout: each corner dword serves BOTH batches; 4 ds_read_b32 (-> 2
// ds_read2_b32) per 2 batch-taps, addr/weight VALU amortized 2x.
__global__ __launch_bounds__(512, 4) void radon_lds_kernel(const uint* __restrict__ ws,
                                                           float* __restrict__ out) {
    __shared__ uint lds[LDSW];

    const int a = blockIdx.x;   // angle
    const int c = blockIdx.y;   // batch pair
    const int h = blockIdx.z;   // y-strip
    const int tid = threadIdx.x;
    const int ystart = 64 * h - 2;               // image row held in LDS row 0

    float ang = (float)a * (float)(M_PI / 179.0);
    float sn, cs;
    sincosf(ang, &sn, &cs);

    // ---- stage strip (zeros outside image/margins) ----
    {
        const uint* __restrict__ src = ws + c * (S * S);
#pragma unroll
        for (int it = 0; it < 36; ++it) {
            int p = it * 512 + tid;
            if (p < LDSW) {
                int r = p / RSW;
                int lx = p - r * RSW;            // 0..264
                int x = lx - 4;                  // image x
                int g = ystart + r;              // image y
                uint d = 0u;
                if (((unsigned)g < 256u) && ((unsigned)x < 256u)) d = src[g * 256 + x];
                lds[p] = d;
            }
        }
    }
    __syncthreads();

    const int j = tid >> 1;      // ray index
    const int q = tid & 1;       // ray segment (lane-minor)

    const float ry = (float)j - 127.5f;
    const float bx = fmaf(-sn, ry, 127.5f);
    const float by = fmaf(cs, ry, 127.5f);
    const float ry2 = ry * ry;

    // disk trim (taps beyond d^2>16934 ~130.13^2 are provably zero)
    float hd = sqrtf(16934.0f - ry2);
    int ilo = max((int)ceilf(127.5f - hd), 0);
    int ihi = min((int)floorf(127.5f + hd) + 1, S);

    // strip ownership: py(i) crosses level L at i = 127.5 + (L-by)/sn.
    float invsn = 1.0f / sn;
    bool neg = (sn < 0.0f);
    float cLo = neg ? (float)(64 * h + 64) : (float)(64 * h);
    float cHi = neg ? (float)(64 * h) : (float)(64 * h + 64);
    float tLo = 127.5f + (cLo - by) * invsn;
    float tHi = 127.5f + (cHi - by) * invsn;
    int FLo = (int)fminf(fmaxf(ceilf(tLo), 0.0f), 256.0f);  // NaN -> 0
    int FHi = (int)fminf(fmaxf(ceilf(tHi), 0.0f), 256.0f);
    bool openLo = (h == (neg ? 3 : 0));
    bool openHi = (h == (neg ? 0 : 3));
    int lo0 = openLo ? ilo : max(ilo, FLo);
    int hi0 = openHi ? ihi : min(ihi, FHi);
    int len = max(hi0 - lo0, 0);
    int lo = lo0 + ((q * len) >> 1);
    int hi = lo0 + (((q + 1) * len) >> 1);

    // folded constants: px_l = cs*i + bxp (includes +4 col offset);
    // py_l = sn*i + byl (local rows: includes -ystart)
    const float bxp = fmaf(-127.5f, cs, bx) + 4.0f;
    const float byl = fmaf(-127.5f, sn, by) - (float)ystart;

    float accA = 0.0f, accB = 0.0f;

#pragma unroll 4
    for (int i = lo; i < hi; ++i) {
        float fi = (float)i;
        float px = fmaf(cs, fi, bxp);
        float py = fmaf(sn, fi, byl);

        float x0f = floorf(px);
        float y0f = floorf(py);
        float wx = px - x0f;
        float wy = py - y0f;
        int xl = (int)x0f;                     // LDS col of x0 (>=0)
        int yl = (int)y0f;                     // LDS row of y0 (>=0)
        int addr = yl * RSW + xl;

        uint d00 = lds[addr];
        uint d10 = lds[addr + 1];
        uint d01 = lds[addr + RSW];
        uint d11 = lds[addr + RSW + 1];

        float ux = 1.0f - wx;
        float uy = 1.0f - wy;
        float w00 = ux * uy;
        float w10 = wx * uy;
        float w01 = ux * wy;
        float w11 = wx * wy;

        accA = fmaf(w00, __half2float(__ushort_as_half((unsigned short)(d00 & 0xffffu))),
               fmaf(w10, __half2float(__ushort_as_half((unsigned short)(d10 & 0xffffu))),
               fmaf(w01, __half2float(__ushort_as_half((unsigned short)(d01 & 0xffffu))),
               fmaf(w11, __half2float(__ushort_as_half((unsigned short)(d11 & 0xffffu))), accA))));
        accB = fmaf(w00, __half2float(__ushort_as_half((unsigned short)(d00 >> 16))),
               fmaf(w10, __half2float(__ushort_as_half((unsigned short)(d10 >> 16))),
               fmaf(w01, __half2float(__ushort_as_half((unsigned short)(d01 >> 16))),
               fmaf(w11, __half2float(__ushort_as_half((unsigned short)(d11 >> 16))), accB))));
    }

    // ---- reduce 2 segments per j, then atomic combine (4 strips deep) ----
    __syncthreads();
    float2* red = (float2*)lds;
    red[tid] = make_float2(accA, accB);
    __syncthreads();
    if (tid < 256) {
        float2 v0 = red[2 * tid];
        float2 v1 = red[2 * tid + 1];
        size_t o = ((size_t)(2 * c) * A + a) * S + tid;
        atomicAdd(&out[o], v0.x + v1.x);
        atomicAdd(&out[o + (size_t)A * S], v0.y + v1.y);
    }
}

extern "C" void kernel_launch(void* const* d_in, const int* in_sizes, int n_in,
                              void* d_out, int out_size, void* d_ws, size_t ws_size,
                              hipStream_t stream) {
    const float* x = (const float*)d_in[0];
    float* out = (float*)d_out;
    uint* ws = (uint*)d_ws;  // 2 * 65536 dwords = 512 KiB

    radon_mask_pack<<<dim3(720), dim3(256), 0, stream>>>(x, ws, out);
    radon_lds_kernel<<<dim3(A, 2, 4), dim3(512), 0, stream>>>(ws, out);
}

// Round 20
// 91.548 us; speedup vs baseline: 1.2004x; 1.2004x over previous
//
#include <hip/hip_runtime.h>
#include <hip/hip_fp16.h>
#include <math.h>

#define S 256
#define A 180
#define B 4
#define NSLOT 18285   // LDS dwords: covers y-mode 69x265 and x-mode 264x69
// y-mode: rows 69 (strip y), stride 265 (odd), cols 264 used (x: -4..259)
// x-mode: rows 264 (y: -4..259), stride 69 (odd), cols 69 used (strip x)

// Kernel 1: circle mask + pack batch-pairs: ws[c*65536+p] = f16(b=2c) | f16(b=2c+1)<<16.
// Also zeroes the output sinogram (grid 720*256 = 184,320 = A*B*S threads).
__global__ void radon_mask_pack(const float* __restrict__ in, uint* __restrict__ ws,
                                float* __restrict__ osino) {
    int idx = blockIdx.x * 256 + threadIdx.x;
    if (idx < 2 * S * S) {
        int c = idx >> 16;
        int p = idx & 65535;
        int y = p >> 8;
        int x = p & 255;
        int dx = x - 128, dy = y - 128;
        bool inside = (dx * dx + dy * dy <= 16384);
        float v0 = in[(2 * c) * (S * S) + p];
        float v1 = in[(2 * c + 1) * (S * S) + p];
        v0 = inside ? v0 : 0.0f;
        v1 = inside ? v1 : 0.0f;
        uint lo = (uint)__half_as_ushort(__float2half(v0));
        uint hi = (uint)__half_as_ushort(__float2half(v1));
        ws[c * (S * S) + p] = lo | (hi << 16);
    }
    if (idx < A * B * S) osino[idx] = 0.0f;
}

// Kernel 2: grid (A, 2 batch-pairs, 4 strips), 1024 thr = (j=tid>>2, q=tid&3).
// ADAPTIVE SPLIT AXIS: strip along y if |sn|>=|cs| else along x -- the split
// coordinate sweeps at rate >= 0.707 along EVERY ray, so every ray owns
// ~64..91 taps in EVERY strip at EVERY angle (R18/R19's axis-angle active-wave
// collapse eliminated). Pair-packed pixels: each corner dword serves both
// batches. 73.1 KB LDS -> 2 blocks/CU = 32 waves, all active.
__global__ __launch_bounds__(1024, 8) void radon_lds_kernel(const uint* __restrict__ ws,
                                                            float* __restrict__ out) {
    __shared__ uint lds[NSLOT];

    const int a = blockIdx.x;   // angle
    const int c = blockIdx.y;   // batch pair
    const int g = blockIdx.z;   // strip
    const int tid = threadIdx.x;

    float ang = (float)a * (float)(M_PI / 179.0);
    float sn, cs;
    sincosf(ang, &sn, &cs);

    const bool ymode = (fabsf(sn) >= fabsf(cs));
    const float rate = ymode ? sn : cs;       // |rate| >= 0.707
    const int wstart = 64 * g - 2;            // split-axis coord in LDS slot 0
    const int st = ymode ? 265 : 69;          // LDS row stride (dwords)

    // ---- stage strip (zeros outside image); wave-uniform mode branch ----
    {
        const uint* __restrict__ src = ws + c * (S * S);
        if (ymode) {
            // rows r=0..68 -> image y = wstart+r ; cols c2=0..263 -> x = c2-4
#pragma unroll
            for (int it = 0; it < 18; ++it) {
                int p = it * 1024 + tid;
                if (p < 69 * 264) {
                    int r = p / 264;
                    int c2 = p - r * 264;
                    int y = wstart + r;
                    int x = c2 - 4;
                    uint d = 0u;
                    if (((unsigned)y < 256u) && ((unsigned)x < 256u)) d = src[y * 256 + x];
                    lds[r * 265 + c2] = d;
                }
            }
        } else {
            // rows r=0..263 -> image y = r-4 ; cols c2=0..68 -> x = wstart+c2
#pragma unroll
            for (int it = 0; it < 18; ++it) {
                int p = it * 1024 + tid;
                if (p < 264 * 69) {
                    int r = p / 69;
                    int c2 = p - r * 69;
                    int y = r - 4;
                    int x = wstart + c2;
                    uint d = 0u;
                    if (((unsigned)y < 256u) && ((unsigned)x < 256u)) d = src[y * 256 + x];
                    lds[p] = d;   // r*69 + c2
                }
            }
        }
    }
    __syncthreads();

    const int j = tid >> 2;      // ray index (16 consecutive j per wave)
    const int q = tid & 3;       // per-ray quarter (lane-minor)

    const float ry = (float)j - 127.5f;
    const float bx = fmaf(-sn, ry, 127.5f);
    const float by = fmaf(cs, ry, 127.5f);
    const float ry2 = ry * ry;

    // disk trim (taps beyond d^2>16934 ~130.13^2 are provably zero)
    float hd = sqrtf(16934.0f - ry2);
    int ilo = max((int)ceilf(127.5f - hd), 0);
    int ihi = min((int)floorf(127.5f + hd) + 1, S);

    // strip ownership on w = (ymode ? py : px) = rate*i + w0;
    // crossing level L at i = 127.5 + (L - w0defl)/rate  (R19-verified logic)
    const float w0 = ymode ? by : bx;
    float invr = 1.0f / rate;                 // |rate|>=0.707: always safe
    bool neg = (rate < 0.0f);
    float cLo = neg ? (float)(64 * g + 64) : (float)(64 * g);
    float cHi = neg ? (float)(64 * g) : (float)(64 * g + 64);
    int FLo = (int)fminf(fmaxf(ceilf(127.5f + (cLo - w0) * invr), 0.0f), 256.0f);
    int FHi = (int)fminf(fmaxf(ceilf(127.5f + (cHi - w0) * invr), 0.0f), 256.0f);
    bool openLo = (g == (neg ? 3 : 0));
    bool openHi = (g == (neg ? 0 : 3));
    int lo0 = openLo ? ilo : max(ilo, FLo);
    int hi0 = openHi ? ihi : min(ihi, FHi);
    int len = max(hi0 - lo0, 0);
    int lo = lo0 + ((q * len) >> 2);
    int hi = lo0 + (((q + 1) * len) >> 2);

    // folded local coords: px_l = cs*i + bxp, py_l = sn*i + byl with
    // y-mode: x offset +4, y offset -wstart ; x-mode: x offset -wstart, y +4
    const float bxp = fmaf(-127.5f, cs, bx) + (ymode ? 4.0f : (float)(-wstart));
    const float byl = fmaf(-127.5f, sn, by) + (ymode ? (float)(-wstart) : 4.0f);

    float accA = 0.0f, accB = 0.0f;

#pragma unroll 4
    for (int i = lo; i < hi; ++i) {
        float fi = (float)i;
        float px = fmaf(cs, fi, bxp);
        float py = fmaf(sn, fi, byl);

        float x0f = floorf(px);
        float y0f = floorf(py);
        float wx = px - x0f;
        float wy = py - y0f;
        int xl = (int)x0f;                 // local col (>=0 by staged margins)
        int yl = (int)y0f;                 // local row (>=0)
        int addr = yl * st + xl;

        uint d00 = lds[addr];
        uint d10 = lds[addr + 1];
        uint d01 = lds[addr + st];
        uint d11 = lds[addr + st + 1];

        float ux = 1.0f - wx;
        float uy = 1.0f - wy;
        float w00 = ux * uy;
        float w10 = wx * uy;
        float w01 = ux * wy;
        float w11 = wx * wy;

        accA = fmaf(w00, __half2float(__ushort_as_half((unsigned short)(d00 & 0xffffu))),
               fmaf(w10, __half2float(__ushort_as_half((unsigned short)(d10 & 0xffffu))),
               fmaf(w01, __half2float(__ushort_as_half((unsigned short)(d01 & 0xffffu))),
               fmaf(w11, __half2float(__ushort_as_half((unsigned short)(d11 & 0xffffu))), accA))));
        accB = fmaf(w00, __half2float(__ushort_as_half((unsigned short)(d00 >> 16))),
               fmaf(w10, __half2float(__ushort_as_half((unsigned short)(d10 >> 16))),
               fmaf(w01, __half2float(__ushort_as_half((unsigned short)(d01 >> 16))),
               fmaf(w11, __half2float(__ushort_as_half((unsigned short)(d11 >> 16))), accB))));
    }

    // ---- reduce 4 quarters per j, then atomic combine (4 strips deep) ----
    __syncthreads();
    float2* red = (float2*)lds;
    red[tid] = make_float2(accA, accB);
    __syncthreads();
    if (tid < 256) {
        float2 v0 = red[4 * tid];
        float2 v1 = red[4 * tid + 1];
        float2 v2 = red[4 * tid + 2];
        float2 v3 = red[4 * tid + 3];
        size_t o = ((size_t)(2 * c) * A + a) * S + tid;
        atomicAdd(&out[o], (v0.x + v1.x) + (v2.x + v3.x));
        atomicAdd(&out[o + (size_t)A * S], (v0.y + v1.y) + (v2.y + v3.y));
    }
}

extern "C" void kernel_launch(void* const* d_in, const int* in_sizes, int n_in,
                              void* d_out, int out_size, void* d_ws, size_t ws_size,
                              hipStream_t stream) {
    const float* x = (const float*)d_in[0];
    float* out = (float*)d_out;
    uint* ws = (uint*)d_ws;  // 2 * 65536 dwords = 512 KiB

    radon_mask_pack<<<dim3(720), dim3(256), 0, stream>>>(x, ws, out);
    radon_lds_kernel<<<dim3(A, 2, 4), dim3(1024), 0, stream>>>(ws, out);
}

// Round 21
// 87.595 us; speedup vs baseline: 1.2546x; 1.0451x over previous
//
#include <hip/hip_runtime.h>
#include <hip/hip_fp16.h>
#include <math.h>

#define S 256
#define A 180
#define B 4
#define NSLOT 18285   // LDS dwords: covers y-mode 69x265 and x-mode 264x69

// Kernel 1: circle mask + pack batch-pairs: ws[c*65536+p] = f16(b=2c) | f16(b=2c+1)<<16.
// Also zeroes the output sinogram (grid 720*256 = 184,320 = A*B*S threads).
__global__ void radon_mask_pack(const float* __restrict__ in, uint* __restrict__ ws,
                                float* __restrict__ osino) {
    int idx = blockIdx.x * 256 + threadIdx.x;
    if (idx < 2 * S * S) {
        int c = idx >> 16;
        int p = idx & 65535;
        int y = p >> 8;
        int x = p & 255;
        int dx = x - 128, dy = y - 128;
        bool inside = (dx * dx + dy * dy <= 16384);
        float v0 = in[(2 * c) * (S * S) + p];
        float v1 = in[(2 * c + 1) * (S * S) + p];
        v0 = inside ? v0 : 0.0f;
        v1 = inside ? v1 : 0.0f;
        uint lo = (uint)__half_as_ushort(__float2half(v0));
        uint hi = (uint)__half_as_ushort(__float2half(v1));
        ws[c * (S * S) + p] = lo | (hi << 16);
    }
    if (idx < A * B * S) osino[idx] = 0.0f;
}

// Kernel 2: grid (A, 2 batch-pairs, 4 strips), 1024 thr = (j=tid>>2, q=tid&3).
// Adaptive split axis (R20-verified): strip along y if |sn|>=|cs| else x; the
// split coordinate sweeps at rate >= 0.707 -> every ray owns ~64..91 taps in
// every strip at every angle. CHANGES vs R20:
// (1) OOB fix: extreme ownership levels clamped to -1/256. Split-axis taps
//     with w < -1 or w >= 256 have BOTH corners outside the image (exact-zero
//     contribution), and R20 let them index lds[..-1] -> garbage with weight
//     ~0.9 (the 0.25->0.94 absmax jump). Interior strip boundaries unchanged
//     (identical float expressions in adjacent blocks -> exact partition).
// (2) Packed-f16 bilinear: corner dwords bitcast to __half2 (batchA,batchB);
//     lerp via __hsub2/__hfma2 with broadcast f16 weights; single f16x2
//     accumulator per thread-segment (<=23 taps), converted to f32 once.
//     Replaces 8 cvt + 8 fma + 6 weight ops with 9 pk ops per pair-tap.
__global__ __launch_bounds__(1024, 8) void radon_lds_kernel(const uint* __restrict__ ws,
                                                            float* __restrict__ out) {
    __shared__ uint lds[NSLOT];

    const int a = blockIdx.x;   // angle
    const int c = blockIdx.y;   // batch pair
    const int g = blockIdx.z;   // strip
    const int tid = threadIdx.x;

    float ang = (float)a * (float)(M_PI / 179.0);
    float sn, cs;
    sincosf(ang, &sn, &cs);

    const bool ymode = (fabsf(sn) >= fabsf(cs));
    const float rate = ymode ? sn : cs;       // |rate| >= 0.707
    const int wstart = 64 * g - 2;            // split-axis coord in LDS slot 0
    const int st = ymode ? 265 : 69;          // LDS row stride (dwords)

    // ---- stage strip (zeros outside image); wave-uniform mode branch ----
    {
        const uint* __restrict__ src = ws + c * (S * S);
        if (ymode) {
#pragma unroll
            for (int it = 0; it < 18; ++it) {
                int p = it * 1024 + tid;
                if (p < 69 * 264) {
                    int r = p / 264;
                    int c2 = p - r * 264;
                    int y = wstart + r;
                    int x = c2 - 4;
                    uint d = 0u;
                    if (((unsigned)y < 256u) && ((unsigned)x < 256u)) d = src[y * 256 + x];
                    lds[r * 265 + c2] = d;
                }
            }
        } else {
#pragma unroll
            for (int it = 0; it < 18; ++it) {
                int p = it * 1024 + tid;
                if (p < 264 * 69) {
                    int r = p / 69;
                    int c2 = p - r * 69;
                    int y = r - 4;
                    int x = wstart + c2;
                    uint d = 0u;
                    if (((unsigned)y < 256u) && ((unsigned)x < 256u)) d = src[y * 256 + x];
                    lds[p] = d;
                }
            }
        }
    }
    __syncthreads();

    const int j = tid >> 2;      // ray index (16 consecutive j per wave)
    const int q = tid & 3;       // per-ray quarter (lane-minor)

    const float ry = (float)j - 127.5f;
    const float bx = fmaf(-sn, ry, 127.5f);
    const float by = fmaf(cs, ry, 127.5f);
    const float ry2 = ry * ry;

    // disk trim (taps beyond d^2>16934 ~130.13^2 are provably zero)
    float hd = sqrtf(16934.0f - ry2);
    int ilo = max((int)ceilf(127.5f - hd), 0);
    int ihi = min((int)floorf(127.5f + hd) + 1, S);

    // strip ownership on w = (ymode ? py : px) = rate*i + w0.
    // Extreme levels clamped to -1 / 256 (exact: outside, both corners OOB).
    const float w0 = ymode ? by : bx;
    float invr = 1.0f / rate;
    bool neg = (rate < 0.0f);
    float cLo, cHi;
    if (!neg) {
        cLo = (g == 0) ? -1.0f : (float)(64 * g);
        cHi = (g == 3) ? 256.0f : (float)(64 * g + 64);
    } else {
        cLo = (g == 3) ? 256.0f : (float)(64 * g + 64);
        cHi = (g == 0) ? -1.0f : (float)(64 * g);
    }
    int FLo = (int)fminf(fmaxf(ceilf(127.5f + (cLo - w0) * invr), 0.0f), 256.0f);
    int FHi = (int)fminf(fmaxf(ceilf(127.5f + (cHi - w0) * invr), 0.0f), 256.0f);
    int lo0 = max(ilo, FLo);
    int hi0 = min(ihi, FHi);
    int len = max(hi0 - lo0, 0);
    int lo = lo0 + ((q * len) >> 2);
    int hi = lo0 + (((q + 1) * len) >> 2);

    // folded local coords: px_l = cs*i + bxp, py_l = sn*i + byl
    const float bxp = fmaf(-127.5f, cs, bx) + (ymode ? 4.0f : (float)(-wstart));
    const float byl = fmaf(-127.5f, sn, by) + (ymode ? (float)(-wstart) : 4.0f);

    __half2 acc2 = __floats2half2_rn(0.0f, 0.0f);

#pragma unroll 4
    for (int i = lo; i < hi; ++i) {
        float fi = (float)i;
        float px = fmaf(cs, fi, bxp);
        float py = fmaf(sn, fi, byl);

        float x0f = floorf(px);
        float y0f = floorf(py);
        float wx = px - x0f;
        float wy = py - y0f;
        int xl = (int)x0f;                 // local col (>=0 by margins + clamp)
        int yl = (int)y0f;                 // local row (>=0)
        int addr = yl * st + xl;

        uint d00 = lds[addr];
        uint d10 = lds[addr + 1];
        uint d01 = lds[addr + st];
        uint d11 = lds[addr + st + 1];

        __half2 h00 = __builtin_bit_cast(__half2, d00);
        __half2 h10 = __builtin_bit_cast(__half2, d10);
        __half2 h01 = __builtin_bit_cast(__half2, d01);
        __half2 h11 = __builtin_bit_cast(__half2, d11);

        __half2 wxh = __float2half2_rn(wx);
        __half2 wyh = __float2half2_rn(wy);

        __half2 r0 = __hfma2(wxh, __hsub2(h10, h00), h00);
        __half2 r1 = __hfma2(wxh, __hsub2(h11, h01), h01);
        acc2 = __hfma2(wyh, __hsub2(r1, r0), __hadd2(acc2, r0));
    }

    float accA = __half2float(__low2half(acc2));
    float accB = __half2float(__high2half(acc2));

    // ---- reduce 4 quarters per j, then atomic combine (4 strips deep) ----
    __syncthreads();
    float2* red = (float2*)lds;
    red[tid] = make_float2(accA, accB);
    __syncthreads();
    if (tid < 256) {
        float2 v0 = red[4 * tid];
        float2 v1 = red[4 * tid + 1];
        float2 v2 = red[4 * tid + 2];
        float2 v3 = red[4 * tid + 3];
        size_t o = ((size_t)(2 * c) * A + a) * S + tid;
        atomicAdd(&out[o], (v0.x + v1.x) + (v2.x + v3.x));
        atomicAdd(&out[o + (size_t)A * S], (v0.y + v1.y) + (v2.y + v3.y));
    }
}

extern "C" void kernel_launch(void* const* d_in, const int* in_sizes, int n_in,
                              void* d_out, int out_size, void* d_ws, size_t ws_size,
                              hipStream_t stream) {
    const float* x = (const float*)d_in[0];
    float* out = (float*)d_out;
    uint* ws = (uint*)d_ws;  // 2 * 65536 dwords = 512 KiB

    radon_mask_pack<<<dim3(720), dim3(256), 0, stream>>>(x, ws, out);
    radon_lds_kernel<<<dim3(A, 2, 4), dim3(1024), 0, stream>>>(ws, out);
}